// Round 10
// baseline (81.914 us; speedup 1.0000x reference)
//
#include <hip/hip_runtime.h>
#include <hip/hip_bf16.h>
#include <math.h>

// Problem constants: B=64, H=384, PLTS=16, D=2, grid 25x25.
#define BB    64
#define HH    384
#define PLTS  16
#define LMAX  (HH + PLTS)      // 400
#define NG    25
#define NC    (NG * NG)        // 625
#define BLOCK 1024             // 16 waves; one block per batch
#define NWAVES (BLOCK / 64)
#define FSTR  388              // padded row stride (floats) for FxT/FyT
#define NCHUNK 8               // K split (384 = 8 x 48)
#define KC    48
#define GEMM_UNITS (125 * NCHUNK)   // (5 kx-groups x 25 ky) x 8 chunks = 1000

#if defined(__has_builtin) && __has_builtin(__builtin_amdgcn_exp2f)
static __device__ __forceinline__ float fast_exp2(float x) { return __builtin_amdgcn_exp2f(x); }
#else
static __device__ __forceinline__ float fast_exp2(float x) { return exp2f(x); }
#endif
#if defined(__has_builtin) && __has_builtin(__builtin_amdgcn_logf)
static __device__ __forceinline__ float fast_log2(float x) { return __builtin_amdgcn_logf(x); }
#else
static __device__ __forceinline__ float fast_log2(float x) { return log2f(x); }
#endif

#if defined(__has_builtin)
#if __has_builtin(__builtin_amdgcn_update_dpp) && __has_builtin(__builtin_amdgcn_readlane)
#define HAS_DPP 1
#endif
#endif

// Wave-wide min, result broadcast to all 64 lanes. Bit-exact (fminf returns an operand).
static __device__ __forceinline__ float wave_min_all(float v) {
#ifdef HAS_DPP
    float r = v;
    // row_shr:1,2,4,8 then row_bcast15 (0x142), row_bcast31 (0x143); old=self -> masked lanes no-op
    #define DPP_STEP(ctrl) { int ri = __float_as_int(r); \
        int si = __builtin_amdgcn_update_dpp(ri, ri, (ctrl), 0xf, 0xf, false); \
        r = fminf(r, __int_as_float(si)); }
    DPP_STEP(0x111) DPP_STEP(0x112) DPP_STEP(0x114) DPP_STEP(0x118)
    DPP_STEP(0x142) DPP_STEP(0x143)
    #undef DPP_STEP
    return __int_as_float(__builtin_amdgcn_readlane(__float_as_int(r), 63));
#else
    for (int o = 1; o < 64; o <<= 1) v = fminf(v, __shfl_xor(v, o, 64));
    return v;
#endif
}

static __device__ __forceinline__ int lane_bcast_int(int x, int src_lane) {
#ifdef HAS_DPP
    return __builtin_amdgcn_readlane(x, src_lane);
#else
    return __shfl(x, src_lane, 64);
#endif
}

__global__ __launch_bounds__(BLOCK)
void spatio_kernel(const float* __restrict__ ct,    // curr_time   (B,16)
                   const float* __restrict__ it,    // input_time  (B,384)
                   const float* __restrict__ hd,    // history_data(B,384,2)
                   const float* __restrict__ beta_p,
                   const float* __restrict__ lsig_p,
                   float* __restrict__ out)         // [B loglik | (16,B,2) preds]
{
    // Separable scan factors: S[kx][ky] = sum_j FxT[kx][j] * FyT[ky][j]
    __shared__ __align__(16) float FxT[NG][FSTR];  // 2^{w_j + c2(cx-hx_j)^2}
    __shared__ __align__(16) float FyT[NG][FSTR];  // 2^{c2(cy-hy_j)^2}
    __shared__ __align__(16) float u_s [LMAX];  // c2*(x^2+y^2) + bl*t  (GMM)
    __shared__ __align__(16) float px_s[LMAX];  // -2*c2*x
    __shared__ __align__(16) float py_s[LMAX];  // -2*c2*y
    __shared__ float  w2s[LMAX];    // bl * t_j   (ALL 400 known pre-fork)
    __shared__ float2 hxy[LMAX];    // history locations
    __shared__ __align__(16) float P[NC * NCHUNK]; // GEMM partials: P[c*8+chunk]
    __shared__ float  Pg[BLOCK];    // GMM row-chunk partials (rows 1..383)
    __shared__ float  rowt[16];     // GMM row totals, rows 384..399
    __shared__ float  pre[LMAX];    // inclusive prefix of E_j = e^{beta t_j}
    __shared__ float  rv[NWAVES];
    __shared__ float  sb[4];        // minx,maxx,miny,maxy

    const int b    = blockIdx.x;
    const int tid  = threadIdx.x;
    const int lane = tid & 63;
    const int wave = tid >> 6;

    const float LOG2E  = 1.4426950408889634f;
    const float LN2    = 0.69314718055994531f;
    const float LOG2PI = 1.8378770664093453f;
    const float INF    = __builtin_inff();

    const float beta  = beta_p[0];
    const float lsig  = lsig_p[0];
    const float sigma = fast_exp2(lsig * LOG2E);
    const float cc    = -0.5f / (sigma * sigma);
    const float c2    = cc * LOG2E;              // base-2 coeff on sq
    const float bl    = beta * LOG2E;            // base-2 coeff on t
    const float Sc    = -2.0f * lsig - LOG2PI;   // d=2 Gaussian const

    // ---- initial history into LDS (hd as float2) ----
    {
        const float2* hd2 = (const float2*)(hd + (size_t)b * HH * 2);
        for (int j = tid; j < HH; j += BLOCK) {
            float t  = it[b * HH + j];
            float2 p = hd2[j];
            float w  = bl * t;
            w2s[j]  = w;
            hxy[j]  = p;
            u_s[j]  = fmaf(c2, p.x * p.x + p.y * p.y, w);
            px_s[j] = -2.0f * c2 * p.x;
            py_s[j] = -2.0f * c2 * p.y;
        }
    }
    // appended-step time weights are prediction-independent: fill w2s[384..399] now
    if (tid < PLTS) w2s[HH + tid] = bl * ct[b * PLTS + tid];

    // wave 0: preload all 16 step weights into registers
    float wn_r[16];
    if (wave == 0) {
        const float4* ct4 = (const float4*)(ct + b * PLTS);
        float4 c0 = ct4[0], c1 = ct4[1], c2v = ct4[2], c3 = ct4[3];
        wn_r[0]=bl*c0.x;  wn_r[1]=bl*c0.y;  wn_r[2]=bl*c0.z;  wn_r[3]=bl*c0.w;
        wn_r[4]=bl*c1.x;  wn_r[5]=bl*c1.y;  wn_r[6]=bl*c1.z;  wn_r[7]=bl*c1.w;
        wn_r[8]=bl*c2v.x; wn_r[9]=bl*c2v.y; wn_r[10]=bl*c2v.z;wn_r[11]=bl*c2v.w;
        wn_r[12]=bl*c3.x; wn_r[13]=bl*c3.y; wn_r[14]=bl*c3.z; wn_r[15]=bl*c3.w;
    } else {
        #pragma unroll
        for (int k = 0; k < 16; ++k) wn_r[k] = 0.0f;
    }

    // ---- grid bounds: min/max of history_data[:,0,:] / [:,1,:] across ALL batches ----
    if (tid < 64) {
        const float* p = hd + tid * (HH * 2);
        float p0x = p[0], p0y = p[1], p1x = p[2], p1y = p[3];
        float xmn = fminf(p0x, p0y), xmx = fmaxf(p0x, p0y);
        float ymn = fminf(p1x, p1y), ymx = fmaxf(p1x, p1y);
        for (int o = 32; o > 0; o >>= 1) {
            xmn = fminf(xmn, __shfl_down(xmn, o, 64));
            xmx = fmaxf(xmx, __shfl_down(xmx, o, 64));
            ymn = fminf(ymn, __shfl_down(ymn, o, 64));
            ymx = fmaxf(ymx, __shfl_down(ymx, o, 64));
        }
        if (tid == 0) { sb[0] = xmn; sb[1] = xmx; sb[2] = ymn; sb[3] = ymx; }
    }
    __syncthreads();

    const float minx = sb[0], maxx = sb[1], miny = sb[2], maxy = sb[3];
    const float stepx = (maxx - minx) * (1.0f / 24.0f);
    const float stepy = (maxy - miny) * (1.0f / 24.0f);

    // ---- separable factor precompute: 2 x 25 x 384 exps ----
    for (int idx = tid; idx < NG * HH; idx += BLOCK) {
        int row = idx / HH;           // grid index 0..24
        int j   = idx - row * HH;     // history point 0..383
        float2 h = hxy[j];
        float cxr = fmaf((float)row, stepx, minx);
        float cyr = fmaf((float)row, stepy, miny);
        float dx = cxr - h.x;
        float dy = cyr - h.y;
        FxT[row][j] = fast_exp2(fmaf(c2 * dx, dx, w2s[j]));
        FyT[row][j] = fast_exp2(c2 * dy * dy);
    }
    __syncthreads();

    // ---- GEMM: 5x1 kx-tiles x K-chunks. unit u = kxg + 5*ky + 125*chunk ----
    if (tid < GEMM_UNITS) {
        int chunk = tid / 125;
        int r     = tid - chunk * 125;
        int ky    = r / 5;
        int kxg   = r - ky * 5;           // 5 consecutive lanes share ky -> Fy broadcast
        const int g0 = chunk * (KC / 4);  // 12 float4-groups per chunk
        const float4* fy4 = (const float4*)&FyT[ky][0];
        const float4* fx0 = (const float4*)&FxT[5 * kxg + 0][0];
        const float4* fx1 = (const float4*)&FxT[5 * kxg + 1][0];
        const float4* fx2 = (const float4*)&FxT[5 * kxg + 2][0];
        const float4* fx3 = (const float4*)&FxT[5 * kxg + 3][0];
        const float4* fx4 = (const float4*)&FxT[5 * kxg + 4][0];
        float4 A0 = {0,0,0,0}, A1 = {0,0,0,0}, A2 = {0,0,0,0}, A3 = {0,0,0,0}, A4 = {0,0,0,0};
        #pragma unroll
        for (int g = g0; g < g0 + KC / 4; ++g) {
            float4 bv = fy4[g];
            float4 x0 = fx0[g];
            A0.x = fmaf(x0.x, bv.x, A0.x); A0.y = fmaf(x0.y, bv.y, A0.y);
            A0.z = fmaf(x0.z, bv.z, A0.z); A0.w = fmaf(x0.w, bv.w, A0.w);
            float4 x1 = fx1[g];
            A1.x = fmaf(x1.x, bv.x, A1.x); A1.y = fmaf(x1.y, bv.y, A1.y);
            A1.z = fmaf(x1.z, bv.z, A1.z); A1.w = fmaf(x1.w, bv.w, A1.w);
            float4 x2 = fx2[g];
            A2.x = fmaf(x2.x, bv.x, A2.x); A2.y = fmaf(x2.y, bv.y, A2.y);
            A2.z = fmaf(x2.z, bv.z, A2.z); A2.w = fmaf(x2.w, bv.w, A2.w);
            float4 x3 = fx3[g];
            A3.x = fmaf(x3.x, bv.x, A3.x); A3.y = fmaf(x3.y, bv.y, A3.y);
            A3.z = fmaf(x3.z, bv.z, A3.z); A3.w = fmaf(x3.w, bv.w, A3.w);
            float4 x4 = fx4[g];
            A4.x = fmaf(x4.x, bv.x, A4.x); A4.y = fmaf(x4.y, bv.y, A4.y);
            A4.z = fmaf(x4.z, bv.z, A4.z); A4.w = fmaf(x4.w, bv.w, A4.w);
        }
        const int cb = 5 * kxg + 25 * ky;      // candidate index of tile element 0
        P[(cb + 0) * NCHUNK + chunk] = (A0.x + A0.y) + (A0.z + A0.w);
        P[(cb + 1) * NCHUNK + chunk] = (A1.x + A1.y) + (A1.z + A1.w);
        P[(cb + 2) * NCHUNK + chunk] = (A2.x + A2.y) + (A2.z + A2.w);
        P[(cb + 3) * NCHUNK + chunk] = (A3.x + A3.y) + (A3.z + A3.w);
        P[(cb + 4) * NCHUNK + chunk] = (A4.x + A4.y) + (A4.z + A4.w);
    }
    __syncthreads();

    // ==== FORK: wave 0 = 16 sequential steps; waves 1..14(+part) = GMM rows 1..383;
    //            wave 15 = prefix scan of E_j (prediction-independent) ====
    if (wave == 0) {
        float Sv[10], cxk[10], cyk[10];
        const int cbase = lane * 10;
        #pragma unroll
        for (int k = 0; k < 10; ++k) {
            int c = cbase + k;
            if (c < NC) {
                const float4* p4 = (const float4*)&P[c * NCHUNK];
                float4 a = p4[0], d = p4[1];
                Sv[k] = ((a.x + a.y) + (a.z + a.w)) + ((d.x + d.y) + (d.z + d.w));
                int ky = (int)((c + 0.5f) * 0.04f);
                int kx = c - 25 * ky;
                cxk[k] = fmaf((float)kx, stepx, minx);
                cyk[k] = fmaf((float)ky, stepy, miny);
            } else {
                Sv[k] = INF; cxk[k] = 0.0f; cyk[k] = 0.0f;
            }
        }
        #pragma unroll
        for (int i = 0; i < PLTS; ++i) {
            // local min (value only), wave-uniform min via DPP, first-occurrence pick
            float vl = Sv[0];
            #pragma unroll
            for (int k = 1; k < 10; ++k) vl = fminf(vl, Sv[k]);
            float vmin = wave_min_all(vl);
            unsigned long long m = __ballot(vl == vmin);
            int win = (int)__ffsll((unsigned long long)m) - 1;   // lowest lane holding the min
            int kl = 9;
            #pragma unroll
            for (int k = 9; k >= 0; --k) if (Sv[k] == vmin) kl = k;  // lowest k on each lane
            int kwin = lane_bcast_int(kl, win);
            int idx  = win * 10 + kwin;
            int   ky = (int)((idx + 0.5f) * 0.04f);
            int   kx = idx - 25 * ky;
            float px = fmaf((float)kx, stepx, minx);
            float py = fmaf((float)ky, stepy, miny);
            float wn = wn_r[i];
            if (lane == 0) {
                const int L = HH + i;
                hxy[L]  = make_float2(px, py);
                u_s[L]  = fmaf(c2, px * px + py * py, wn);
                px_s[L] = -2.0f * c2 * px;
                py_s[L] = -2.0f * c2 * py;
                out[BB + (i * BB + b) * 2 + 0] = px;
                out[BB + (i * BB + b) * 2 + 1] = py;
            }
            #pragma unroll
            for (int k = 0; k < 10; ++k) {
                float dx = px - cxk[k], dy = py - cyk[k];
                Sv[k] += fast_exp2(fmaf(c2, fmaf(dx, dx, dy * dy), wn));
            }
        }
    } else {
        const int t2 = tid - 64;
        if (t2 < 812) {
            // GMM rows 1..383, chunks of <=120 pairs:
            //   t2   0..119 : row = t2+1          c=0          (rows 1..120)
            //   t2 120..359 : row = 121+(u>>1)    c=u&1        (rows 121..240)
            //   t2 360..719 : row = 241+u/3       c=u-3*(u/3)  (rows 241..360)
            //   t2 720..811 : row = 361+(u>>2)    c=u&3, 96/ch (rows 361..383)
            int row, c, csz;
            if (t2 < 120)      { row = t2 + 1; c = 0; csz = 120; }
            else if (t2 < 360) { int u = t2 - 120; row = 121 + (u >> 1); c = u & 1; csz = 120; }
            else if (t2 < 720) { int u = t2 - 360; int q = u / 3; row = 241 + q; c = u - 3 * q; csz = 120; }
            else               { int u = t2 - 720; row = 361 + (u >> 2); c = u & 3; csz = 96; }
            int j0 = c * csz;                 // multiple of 4
            int j1 = min(row, j0 + csz);
            float part = 0.0f;
            {
                float2 hi = hxy[row];
                float xi = hi.x, yi = hi.y;
                float Ai = c2 * fmaf(xi, xi, yi * yi);
                const float4* u4g  = (const float4*)u_s;
                const float4* px4g = (const float4*)px_s;
                const float4* py4g = (const float4*)py_s;
                float a0 = 0.f, a1 = 0.f, a2 = 0.f, a3 = 0.f;
                int j = j0;
                for (; j + 4 <= j1; j += 4) {
                    int g = j >> 2;
                    float4 U = u4g[g], PX = px4g[g], PY = py4g[g];
                    a0 += fast_exp2(fmaf(PX.x, xi, fmaf(PY.x, yi, U.x + Ai)));
                    a1 += fast_exp2(fmaf(PX.y, xi, fmaf(PY.y, yi, U.y + Ai)));
                    a2 += fast_exp2(fmaf(PX.z, xi, fmaf(PY.z, yi, U.z + Ai)));
                    a3 += fast_exp2(fmaf(PX.w, xi, fmaf(PY.w, yi, U.w + Ai)));
                }
                for (; j < j1; ++j)
                    a0 += fast_exp2(fmaf(px_s[j], xi, fmaf(py_s[j], yi, u_s[j] + Ai)));
                part = (a0 + a1) + (a2 + a3);
            }
            Pg[tid] = part;
        } else if (t2 >= 896) {
            // wave 15: inclusive prefix of E_j = 2^{w2s[j]}, 7 elements/lane
            const int i0 = lane * 7;
            float e0=0,e1=0,e2=0,e3=0,e4=0,e5=0,e6=0;
            float s = 0.0f;
            if (i0 < LMAX) {
                s = fast_exp2(w2s[i0]);                                e0 = s;
                if (i0+1 < LMAX) { s += fast_exp2(w2s[i0+1]); }        e1 = s;
                if (i0+2 < LMAX) { s += fast_exp2(w2s[i0+2]); }        e2 = s;
                if (i0+3 < LMAX) { s += fast_exp2(w2s[i0+3]); }        e3 = s;
                if (i0+4 < LMAX) { s += fast_exp2(w2s[i0+4]); }        e4 = s;
                if (i0+5 < LMAX) { s += fast_exp2(w2s[i0+5]); }        e5 = s;
                if (i0+6 < LMAX) { s += fast_exp2(w2s[i0+6]); }        e6 = s;
            }
            float inc = s;
            for (int o = 1; o < 64; o <<= 1) {
                float y = __shfl_up(inc, o, 64);
                if (lane >= o) inc += y;
            }
            float off = inc - s;
            if (i0 < LMAX) {
                pre[i0] = e0 + off;
                if (i0+1 < LMAX) pre[i0+1] = e1 + off;
                if (i0+2 < LMAX) pre[i0+2] = e2 + off;
                if (i0+3 < LMAX) pre[i0+3] = e3 + off;
                if (i0+4 < LMAX) pre[i0+4] = e4 + off;
                if (i0+5 < LMAX) pre[i0+5] = e5 + off;
                if (i0+6 < LMAX) pre[i0+6] = e6 + off;
            }
        }
    }
    __syncthreads();

    // ---- GMM tail rows 384..399: row = 384+wave, 64 chunks of <=7 pairs ----
    {
        const int row = HH + wave;           // 384..399
        int j0 = lane * 7;
        int j1 = min(row, j0 + 7);
        float2 hi = hxy[row];
        float xi = hi.x, yi = hi.y;
        float Ai = c2 * fmaf(xi, xi, yi * yi);
        float part = 0.0f;
        for (int j = j0; j < j1; ++j)
            part += fast_exp2(fmaf(px_s[j], xi, fmaf(py_s[j], yi, u_s[j] + Ai)));
        for (int o = 32; o > 0; o >>= 1) part += __shfl_down(part, o, 64);
        if (lane == 0) rowt[wave] = part;
    }
    __syncthreads();

    // ---- per-row logp + block reduction ----
    float acc = 0.0f;
    if (tid >= 1 && tid < LMAX) {
        const int row = tid;
        float tot;
        if (row <= 120)      { tot = Pg[64 + row - 1]; }
        else if (row <= 240) { int base = 64 + 120 + (row - 121) * 2;
                               tot = Pg[base] + Pg[base + 1]; }
        else if (row <= 360) { int base = 64 + 360 + (row - 241) * 3;
                               tot = Pg[base] + Pg[base + 1] + Pg[base + 2]; }
        else if (row <= 383) { int base = 64 + 720 + (row - 361) * 4;
                               tot = (Pg[base] + Pg[base + 1]) + (Pg[base + 2] + Pg[base + 3]); }
        else                 { tot = rowt[row - HH]; }
        acc = Sc + LN2 * (fast_log2(tot) - fast_log2(pre[row - 1]));
    }
    for (int o = 32; o > 0; o >>= 1) acc += __shfl_down(acc, o, 64);
    if (lane == 0) rv[wave] = acc;
    __syncthreads();
    if (tid == 0) {
        float tot = 0.0f;
        for (int w = 0; w < NWAVES; ++w) tot += rv[w];
        float2 h0 = hxy[0];
        tot += -0.5f * (h0.x * h0.x + h0.y * h0.y) - LOG2PI;
        out[b] = tot;
    }
}

extern "C" void kernel_launch(void* const* d_in, const int* in_sizes, int n_in,
                              void* d_out, int out_size, void* d_ws, size_t ws_size,
                              hipStream_t stream) {
    const float* ct   = (const float*)d_in[0]; // curr_time
    const float* it   = (const float*)d_in[1]; // input_time
    const float* hd   = (const float*)d_in[2]; // history_data
    // d_in[3..5] (expected_data, aux_state_in, aux_state_out) are dead in the math
    const float* beta = (const float*)d_in[6];
    const float* lsig = (const float*)d_in[7];
    float* out = (float*)d_out;

    hipLaunchKernelGGL(spatio_kernel, dim3(BB), dim3(BLOCK), 0, stream,
                       ct, it, hd, beta, lsig, out);
}